// Round 3
// baseline (74.506 us; speedup 1.0000x reference)
//
#include <hip/hip_runtime.h>
#include <math.h>

#define B_ 64
#define T_ 2048
#define D_ 512
#define K_ 8
#define NCHUNK 8
#define ROWS_PER_CHUNK (T_ / NCHUNK)            // 256
#define WAVES 4
#define THREADS (WAVES * 64)                    // 256
#define ROWS_PER_WAVE (ROWS_PER_CHUNK / WAVES)  // 64
#define PAIRS (ROWS_PER_WAVE / 2)               // 32

// --- wave64 all-reduce sum: 4 DPP row_ror rounds (VALU pipe) + 2 cross-row
//     shuffles (DS pipe). 16 independent instances per row-pair pipeline well.
template <int CTRL>
__device__ __forceinline__ float dpp_add(float v) {
  int vi = __builtin_bit_cast(int, v);
  int sh = __builtin_amdgcn_update_dpp(0, vi, CTRL, 0xF, 0xF, true);
  return v + __builtin_bit_cast(float, sh);
}

__device__ __forceinline__ float wave_sum(float v) {
  v = dpp_add<0x121>(v);  // row_ror:1
  v = dpp_add<0x122>(v);  // row_ror:2
  v = dpp_add<0x124>(v);  // row_ror:4
  v = dpp_add<0x128>(v);  // row_ror:8  -> full sum within each 16-lane row
  v += __shfl_xor(v, 16);
  v += __shfl_xor(v, 32);
  return v;
}

// Kernel 1: fused logits -> softmax -> weighted accumulation, single pass
// over x. Occupancy is VGPR-capped at 2 waves/SIMD (w[64]+acc[64] are
// irreducible), so latency hiding comes from a 3-stage row-pair pipeline:
// loads issued 2 iterations (~1700 VALU cycles) before first use, covering
// the ~900-cycle HBM miss latency.
__global__ __launch_bounds__(THREADS, 2) void k1_accum(
    const float* __restrict__ x, const float* __restrict__ attn_w,
    const float* __restrict__ attn_b, float* __restrict__ ax_part,
    float* __restrict__ asum_part) {
  const int blk = blockIdx.x;
  const int b = blk / NCHUNK;
  const int chunk = blk % NCHUNK;
  const int tid = threadIdx.x;
  const int wave = tid >> 6;
  const int lane = tid & 63;
  const int dbase = lane << 3;  // 8 d's per lane

  float w[K_][8];
#pragma unroll
  for (int k = 0; k < K_; ++k) {
    const float4 w0 = *reinterpret_cast<const float4*>(attn_w + k * D_ + dbase);
    const float4 w1 = *reinterpret_cast<const float4*>(attn_w + k * D_ + dbase + 4);
    w[k][0] = w0.x; w[k][1] = w0.y; w[k][2] = w0.z; w[k][3] = w0.w;
    w[k][4] = w1.x; w[k][5] = w1.y; w[k][6] = w1.z; w[k][7] = w1.w;
  }
  float bias[K_];
#pragma unroll
  for (int k = 0; k < K_; ++k) bias[k] = attn_b[k];

  float acc[K_][8];
  float asum[K_];
#pragma unroll
  for (int k = 0; k < K_; ++k) {
    asum[k] = 0.f;
#pragma unroll
    for (int j = 0; j < 8; ++j) acc[k][j] = 0.f;
  }

  const float* xrow = x + ((size_t)b * T_ + (size_t)chunk * ROWS_PER_CHUNK +
                           (size_t)wave * ROWS_PER_WAVE) * (size_t)D_ + dbase;

  // 3-stage pipeline: A = consume now, B = next, C = just loaded.
  float4 a00 = *reinterpret_cast<const float4*>(xrow + 0 * D_);
  float4 a01 = *reinterpret_cast<const float4*>(xrow + 0 * D_ + 4);
  float4 a10 = *reinterpret_cast<const float4*>(xrow + 1 * D_);
  float4 a11 = *reinterpret_cast<const float4*>(xrow + 1 * D_ + 4);
  float4 b00 = *reinterpret_cast<const float4*>(xrow + 2 * D_);
  float4 b01 = *reinterpret_cast<const float4*>(xrow + 2 * D_ + 4);
  float4 b10 = *reinterpret_cast<const float4*>(xrow + 3 * D_);
  float4 b11 = *reinterpret_cast<const float4*>(xrow + 3 * D_ + 4);
  float4 q00 = *reinterpret_cast<const float4*>(xrow + 4 * D_);
  float4 q01 = *reinterpret_cast<const float4*>(xrow + 4 * D_ + 4);
  float4 q10 = *reinterpret_cast<const float4*>(xrow + 5 * D_);
  float4 q11 = *reinterpret_cast<const float4*>(xrow + 5 * D_ + 4);

  for (int r = 0; r < PAIRS; ++r) {
    // issue loads for pair r+3 (consumed 3 iterations from now), clamped
    const int rown = (2 * r + 6 < ROWS_PER_WAVE) ? (2 * r + 6) : (ROWS_PER_WAVE - 2);
    const float* nxt = xrow + (size_t)rown * D_;
    const float4 n00 = *reinterpret_cast<const float4*>(nxt);
    const float4 n01 = *reinterpret_cast<const float4*>(nxt + 4);
    const float4 n10 = *reinterpret_cast<const float4*>(nxt + D_);
    const float4 n11 = *reinterpret_cast<const float4*>(nxt + D_ + 4);

    const float xv0[8] = {a00.x, a00.y, a00.z, a00.w, a01.x, a01.y, a01.z, a01.w};
    const float xv1[8] = {a10.x, a10.y, a10.z, a10.w, a11.x, a11.y, a11.z, a11.w};

    // per-lane partial dots for all 8 clusters, both rows (16 indep chains)
    float p0[K_], p1[K_];
#pragma unroll
    for (int k = 0; k < K_; ++k) {
      float s0 = xv0[0] * w[k][0];
      float s1 = xv1[0] * w[k][0];
#pragma unroll
      for (int j = 1; j < 8; ++j) {
        s0 = fmaf(xv0[j], w[k][j], s0);
        s1 = fmaf(xv1[j], w[k][j], s1);
      }
      p0[k] = s0;
      p1[k] = s1;
    }
#pragma unroll
    for (int k = 0; k < K_; ++k) {
      p0[k] = wave_sum(p0[k]);
      p1[k] = wave_sum(p1[k]);
    }

    // softmax over K=8 without max-subtraction: logits ~ N(0,1), exp safe in
    // fp32; mathematically identical to the max-subtracted form.
    float s0 = 0.f, s1 = 0.f;
    float e0[K_], e1[K_];
#pragma unroll
    for (int k = 0; k < K_; ++k) {
      e0[k] = __expf(p0[k] + bias[k]);
      e1[k] = __expf(p1[k] + bias[k]);
      s0 += e0[k];
      s1 += e1[k];
    }
    const float inv0 = __builtin_amdgcn_rcpf(s0);
    const float inv1 = __builtin_amdgcn_rcpf(s1);

#pragma unroll
    for (int k = 0; k < K_; ++k) {
      const float a0 = e0[k] * inv0;
      const float a1 = e1[k] * inv1;
      asum[k] += a0 + a1;
#pragma unroll
      for (int j = 0; j < 8; ++j)
        acc[k][j] = fmaf(a0, xv0[j], fmaf(a1, xv1[j], acc[k][j]));
    }
    // rotate pipeline (static names -> stays in registers)
    a00 = b00; a01 = b01; a10 = b10; a11 = b11;
    b00 = q00; b01 = q01; b10 = q10; b11 = q11;
    q00 = n00; q01 = n01; q10 = n10; q11 = n11;
  }

  // cross-wave reduction in LDS (sequential rounds -> deterministic)
  __shared__ __align__(16) float lds_ax[K_ * D_];  // 16 KiB
  __shared__ float lds_asum[WAVES][K_];
  if (lane == 0) {
#pragma unroll
    for (int k = 0; k < K_; ++k) lds_asum[wave][k] = asum[k];
  }
  for (int wv = 0; wv < WAVES; ++wv) {
    if (wave == wv) {
      if (wv == 0) {
#pragma unroll
        for (int k = 0; k < K_; ++k)
#pragma unroll
          for (int j = 0; j < 8; ++j) lds_ax[k * D_ + dbase + j] = acc[k][j];
      } else {
#pragma unroll
        for (int k = 0; k < K_; ++k)
#pragma unroll
          for (int j = 0; j < 8; ++j) lds_ax[k * D_ + dbase + j] += acc[k][j];
      }
    }
    __syncthreads();
  }

  float4* outp = reinterpret_cast<float4*>(ax_part + (size_t)blk * (K_ * D_));
  const float4* lp = reinterpret_cast<const float4*>(lds_ax);
#pragma unroll
  for (int i = 0; i < (K_ * D_ / 4) / THREADS; ++i)  // 4 iters
    outp[tid + i * THREADS] = lp[tid + i * THREADS];
  if (tid < K_) {
    float s = 0.f;
#pragma unroll
    for (int wv = 0; wv < WAVES; ++wv) s += lds_asum[wv][tid];
    asum_part[blk * K_ + tid] = s;
  }
}

// Kernel 2: reduce chunk partials, subtract asum*centers, L2-normalize per b.
// 1024 threads/block: 4 elems/thread keeps the dependent-load chain short.
#define K2_THREADS 1024
__global__ __launch_bounds__(K2_THREADS) void k2_finalize(
    const float* __restrict__ ax_part, const float* __restrict__ asum_part,
    const float* __restrict__ centers, float* __restrict__ out) {
  const int b = blockIdx.x;
  const int tid = threadIdx.x;
  const int wave = tid >> 6;
  const int lane = tid & 63;

  __shared__ float s_asum[K_];
  if (tid < K_) {
    float s = 0.f;
#pragma unroll
    for (int c = 0; c < NCHUNK; ++c) s += asum_part[(b * NCHUNK + c) * K_ + tid];
    s_asum[tid] = s;
  }
  __syncthreads();

  const int NPT = (K_ * D_) / K2_THREADS;  // 4
  float pooled[NPT];
  float sq = 0.f;
  const float* base = ax_part + (size_t)b * NCHUNK * (K_ * D_);
#pragma unroll
  for (int i = 0; i < NPT; ++i) {
    const int idx = tid + i * K2_THREADS;
    float v = 0.f;
#pragma unroll
    for (int c = 0; c < NCHUNK; ++c) v += base[(size_t)c * (K_ * D_) + idx];
    const int k = idx >> 9;  // idx / D_
    v -= s_asum[k] * centers[idx];
    pooled[i] = v;
    sq = fmaf(v, v, sq);
  }

#pragma unroll
  for (int m = 32; m; m >>= 1) sq += __shfl_xor(sq, m);
  __shared__ float s_sq[K2_THREADS / 64];
  if (lane == 0) s_sq[wave] = sq;
  __syncthreads();
  float tot = 0.f;
#pragma unroll
  for (int wv = 0; wv < K2_THREADS / 64; ++wv) tot += s_sq[wv];
  const float invn = 1.0f / fmaxf(sqrtf(tot), 1e-12f);

#pragma unroll
  for (int i = 0; i < NPT; ++i)
    out[(size_t)b * (K_ * D_) + tid + i * K2_THREADS] = pooled[i] * invn;
}

extern "C" void kernel_launch(void* const* d_in, const int* in_sizes, int n_in,
                              void* d_out, int out_size, void* d_ws, size_t ws_size,
                              hipStream_t stream) {
  (void)in_sizes; (void)n_in; (void)out_size; (void)ws_size;
  const float* x = (const float*)d_in[0];
  const float* centers = (const float*)d_in[1];
  const float* attn_w = (const float*)d_in[2];
  const float* attn_b = (const float*)d_in[3];
  float* out = (float*)d_out;

  float* ax_part = (float*)d_ws;                               // B*NCHUNK*K*D floats (8 MiB)
  float* asum_part = ax_part + (size_t)B_ * NCHUNK * K_ * D_;  // B*NCHUNK*K floats

  k1_accum<<<B_ * NCHUNK, THREADS, 0, stream>>>(x, attn_w, attn_b, ax_part, asum_part);
  k2_finalize<<<B_, K2_THREADS, 0, stream>>>(ax_part, asum_part, centers, out);
}

// Round 6
// 70.973 us; speedup vs baseline: 1.0498x; 1.0498x over previous
//
#include <hip/hip_runtime.h>

#define B_ 64
#define T_ 2048
#define D_ 512
#define K_ 8
#define NCHUNK 8
#define ROWS_PER_CHUNK (T_ / NCHUNK)            // 256
#define WAVES 4
#define THREADS (WAVES * 64)                    // 256
#define ROWS_PER_WAVE (ROWS_PER_CHUNK / WAVES)  // 64
#define PAIRS (ROWS_PER_WAVE / 2)               // 32
#define LOG2E 1.44269504088896340736f

// device exp2: direct v_exp_f32 builtin (plain __exp2f collides with a glibc
// math.h prototype -- round-5 compile failure)
__device__ __forceinline__ float dev_exp2(float v) {
  return __builtin_amdgcn_exp2f(v);
}

// Wave64 all-reduce (round-2 proven): 4 DPP row_ror rounds via
// __builtin_amdgcn_update_dpp (compiler handles DPP read-after-VALU-write
// hazard nops -- raw asm DPP corrupted results in round 4), then 2 DS
// shuffles for the cross-row halves.
template <int CTRL>
__device__ __forceinline__ float dpp_add(float v) {
  int vi = __builtin_bit_cast(int, v);
  int sh = __builtin_amdgcn_update_dpp(0, vi, CTRL, 0xF, 0xF, true);
  return v + __builtin_bit_cast(float, sh);
}

__device__ __forceinline__ float wave_sum(float v) {
  v = dpp_add<0x121>(v);  // row_ror:1
  v = dpp_add<0x122>(v);  // row_ror:2
  v = dpp_add<0x124>(v);  // row_ror:4
  v = dpp_add<0x128>(v);  // row_ror:8  -> full sum within each 16-lane row
  v += __shfl_xor(v, 16);
  v += __shfl_xor(v, 32);
  return v;
}

// Kernel 1: fused logits -> softmax -> weighted accumulation, single pass
// over x. 2 waves/SIMD (VGPR-capped); ping-pong row-pair buffers (unroll-2,
// no rotation movs). Lane owns d in {lane*4..+4} u {256+lane*4..+4} so each
// dwordx4 wave-load is a contiguous 1KB segment. w/bias pre-scaled by log2e
// so softmax uses v_exp directly (exp2) -- logits feed ONLY softmax, acc uses
// raw xv, so the scaling is mathematically transparent.
__global__ __launch_bounds__(THREADS, 2) void k1_accum(
    const float* __restrict__ x, const float* __restrict__ attn_w,
    const float* __restrict__ attn_b, float* __restrict__ ax_part,
    float* __restrict__ asum_part) {
  const int blk = blockIdx.x;
  const int b = blk / NCHUNK;
  const int chunk = blk % NCHUNK;
  const int tid = threadIdx.x;
  const int wave = tid >> 6;
  const int lane = tid & 63;
  const int lane4 = lane << 2;

  float w[K_][8];
#pragma unroll
  for (int k = 0; k < K_; ++k) {
    const float4 w0 = *reinterpret_cast<const float4*>(attn_w + k * D_ + lane4);
    const float4 w1 = *reinterpret_cast<const float4*>(attn_w + k * D_ + 256 + lane4);
    w[k][0] = w0.x * LOG2E; w[k][1] = w0.y * LOG2E;
    w[k][2] = w0.z * LOG2E; w[k][3] = w0.w * LOG2E;
    w[k][4] = w1.x * LOG2E; w[k][5] = w1.y * LOG2E;
    w[k][6] = w1.z * LOG2E; w[k][7] = w1.w * LOG2E;
  }
  float bias[K_];
#pragma unroll
  for (int k = 0; k < K_; ++k) bias[k] = attn_b[k] * LOG2E;

  float acc[K_][8];
  float asum[K_];
#pragma unroll
  for (int k = 0; k < K_; ++k) {
    asum[k] = 0.f;
#pragma unroll
    for (int j = 0; j < 8; ++j) acc[k][j] = 0.f;
  }

  const float* xw = x + ((size_t)b * T_ + (size_t)chunk * ROWS_PER_CHUNK +
                         (size_t)wave * ROWS_PER_WAVE) * (size_t)D_;

#define LOADPAIR(P00, P01, P10, P11, pairidx)                                  \
  do {                                                                         \
    const float* rp_ = xw + (size_t)(2 * (pairidx)) * D_;                      \
    P00 = *reinterpret_cast<const float4*>(rp_ + lane4);                       \
    P01 = *reinterpret_cast<const float4*>(rp_ + 256 + lane4);                 \
    P10 = *reinterpret_cast<const float4*>(rp_ + D_ + lane4);                  \
    P11 = *reinterpret_cast<const float4*>(rp_ + D_ + 256 + lane4);            \
  } while (0)

  auto process = [&](const float4& r0lo, const float4& r0hi,
                     const float4& r1lo, const float4& r1hi) {
    const float xv0[8] = {r0lo.x, r0lo.y, r0lo.z, r0lo.w,
                          r0hi.x, r0hi.y, r0hi.z, r0hi.w};
    const float xv1[8] = {r1lo.x, r1lo.y, r1lo.z, r1lo.w,
                          r1hi.x, r1hi.y, r1hi.z, r1hi.w};
    float p0[K_], p1[K_];
#pragma unroll
    for (int k = 0; k < K_; ++k) {
      float s0 = xv0[0] * w[k][0];
      float s1 = xv1[0] * w[k][0];
#pragma unroll
      for (int j = 1; j < 8; ++j) {
        s0 = fmaf(xv0[j], w[k][j], s0);
        s1 = fmaf(xv1[j], w[k][j], s1);
      }
      p0[k] = s0;
      p1[k] = s1;
    }
#pragma unroll
    for (int k = 0; k < K_; ++k) {
      p0[k] = wave_sum(p0[k]);
      p1[k] = wave_sum(p1[k]);
    }
    // softmax over K=8 in exp2 domain (w,bias pre-scaled by log2e); no
    // max-subtraction: logits ~ N(0,1), exp2 safe in fp32 and the ratio is
    // mathematically identical to the max-subtracted form.
    float s0 = 0.f, s1 = 0.f;
    float e0[K_], e1[K_];
#pragma unroll
    for (int k = 0; k < K_; ++k) {
      e0[k] = dev_exp2(p0[k] + bias[k]);
      e1[k] = dev_exp2(p1[k] + bias[k]);
      s0 += e0[k];
      s1 += e1[k];
    }
    const float inv0 = __builtin_amdgcn_rcpf(s0);
    const float inv1 = __builtin_amdgcn_rcpf(s1);
#pragma unroll
    for (int k = 0; k < K_; ++k) {
      const float a0 = e0[k] * inv0;
      const float a1 = e1[k] * inv1;
      asum[k] += a0 + a1;
#pragma unroll
      for (int j = 0; j < 8; ++j)
        acc[k][j] = fmaf(a0, xv0[j], fmaf(a1, xv1[j], acc[k][j]));
    }
  };

  float4 A00, A01, A10, A11, B00, B01, B10, B11;
  LOADPAIR(A00, A01, A10, A11, 0);
  LOADPAIR(B00, B01, B10, B11, 1);

  for (int p = 0; p < PAIRS; p += 2) {
    process(A00, A01, A10, A11);
    const int pa = (p + 2 < PAIRS) ? (p + 2) : p;  // clamped refill (in-bounds)
    LOADPAIR(A00, A01, A10, A11, pa);
    process(B00, B01, B10, B11);
    const int pb = (p + 3 < PAIRS) ? (p + 3) : (p + 1);
    LOADPAIR(B00, B01, B10, B11, pb);
  }
#undef LOADPAIR

  // cross-wave reduction in LDS (sequential rounds -> deterministic)
  __shared__ __align__(16) float lds_ax[K_ * D_];  // 16 KiB
  __shared__ float lds_asum[WAVES][K_];
  if (lane == 0) {
#pragma unroll
    for (int k = 0; k < K_; ++k) lds_asum[wave][k] = asum[k];
  }
  for (int wv = 0; wv < WAVES; ++wv) {
    if (wave == wv) {
      if (wv == 0) {
#pragma unroll
        for (int k = 0; k < K_; ++k)
#pragma unroll
          for (int j = 0; j < 8; ++j) {
            const int d = (j < 4) ? (lane4 + j) : (256 + lane4 + j - 4);
            lds_ax[k * D_ + d] = acc[k][j];
          }
      } else {
#pragma unroll
        for (int k = 0; k < K_; ++k)
#pragma unroll
          for (int j = 0; j < 8; ++j) {
            const int d = (j < 4) ? (lane4 + j) : (256 + lane4 + j - 4);
            lds_ax[k * D_ + d] += acc[k][j];
          }
      }
    }
    __syncthreads();
  }

  float4* outp = reinterpret_cast<float4*>(ax_part + (size_t)blk * (K_ * D_));
  const float4* lp = reinterpret_cast<const float4*>(lds_ax);
#pragma unroll
  for (int i = 0; i < (K_ * D_ / 4) / THREADS; ++i)  // 4 iters
    outp[tid + i * THREADS] = lp[tid + i * THREADS];
  if (tid < K_) {
    float s = 0.f;
#pragma unroll
    for (int wv = 0; wv < WAVES; ++wv) s += lds_asum[wv][tid];
    asum_part[blk * K_ + tid] = s;
  }
}

// Kernel 2: reduce chunk partials, subtract asum*centers, L2-normalize per b.
#define K2_THREADS 1024
__global__ __launch_bounds__(K2_THREADS) void k2_finalize(
    const float* __restrict__ ax_part, const float* __restrict__ asum_part,
    const float* __restrict__ centers, float* __restrict__ out) {
  const int b = blockIdx.x;
  const int tid = threadIdx.x;
  const int wave = tid >> 6;
  const int lane = tid & 63;

  __shared__ float s_asum[K_];
  if (tid < K_) {
    float s = 0.f;
#pragma unroll
    for (int c = 0; c < NCHUNK; ++c) s += asum_part[(b * NCHUNK + c) * K_ + tid];
    s_asum[tid] = s;
  }
  __syncthreads();

  const int NPT = (K_ * D_) / K2_THREADS;  // 4
  float pooled[NPT];
  float sq = 0.f;
  const float* base = ax_part + (size_t)b * NCHUNK * (K_ * D_);
#pragma unroll
  for (int i = 0; i < NPT; ++i) {
    const int idx = tid + i * K2_THREADS;
    float v = 0.f;
#pragma unroll
    for (int c = 0; c < NCHUNK; ++c) v += base[(size_t)c * (K_ * D_) + idx];
    const int k = idx >> 9;  // idx / D_
    v -= s_asum[k] * centers[idx];
    pooled[i] = v;
    sq = fmaf(v, v, sq);
  }

#pragma unroll
  for (int m = 32; m; m >>= 1) sq += __shfl_xor(sq, m);
  __shared__ float s_sq[K2_THREADS / 64];
  if (lane == 0) s_sq[wave] = sq;
  __syncthreads();
  float tot = 0.f;
#pragma unroll
  for (int wv = 0; wv < K2_THREADS / 64; ++wv) tot += s_sq[wv];
  const float invn = 1.0f / fmaxf(__builtin_sqrtf(tot), 1e-12f);

#pragma unroll
  for (int i = 0; i < NPT; ++i)
    out[(size_t)b * (K_ * D_) + tid + i * K2_THREADS] = pooled[i] * invn;
}

extern "C" void kernel_launch(void* const* d_in, const int* in_sizes, int n_in,
                              void* d_out, int out_size, void* d_ws, size_t ws_size,
                              hipStream_t stream) {
  (void)in_sizes; (void)n_in; (void)out_size; (void)ws_size;
  const float* x = (const float*)d_in[0];
  const float* centers = (const float*)d_in[1];
  const float* attn_w = (const float*)d_in[2];
  const float* attn_b = (const float*)d_in[3];
  float* out = (float*)d_out;

  float* ax_part = (float*)d_ws;                               // B*NCHUNK*K*D floats (8 MiB)
  float* asum_part = ax_part + (size_t)B_ * NCHUNK * K_ * D_;  // B*NCHUNK*K floats

  k1_accum<<<B_ * NCHUNK, THREADS, 0, stream>>>(x, attn_w, attn_b, ax_part, asum_part);
  k2_finalize<<<B_, K2_THREADS, 0, stream>>>(ax_part, asum_part, centers, out);
}